// Round 3
// baseline (9218.243 us; speedup 1.0000x reference)
//
#include <hip/hip_runtime.h>
#include <hip/hip_bf16.h>

#define N_NODES 10000
#define N_EDGES 320000
#define D_NODE 32
#define D_RAD 8
#define D_SPH 9
#define LAT 64
#define NHEAD 8
#define NL 2
#define GEN_W 280
#define ENV_USED 216   // reference only uses env[:, :216]
#define WN_ENV 24
#define WN_FIN 1536

#define RS136 0.08574929257125442f   // 136^-0.5
#define RS8   0.35355339059327373f   // 8^-0.5

__device__ __forceinline__ int irrep_of(int d){ return (d==0)?0:((d<4)?1:2); }

__device__ __forceinline__ float wave_sum(float v){
  #pragma unroll
  for (int off=32; off; off>>=1) v += __shfl_xor(v, off);
  return v;
}

__device__ __forceinline__ void atomicMaxF(float* addr, float v){
  if (v >= 0.f) atomicMax((int*)addr, __float_as_int(v));
  else          atomicMin((unsigned int*)addr, __float_as_uint(v));
}

__global__ void fill_neg_inf(float* p, int n){
  int i = blockIdx.x*blockDim.x + threadIdx.x;
  if (i < n) p[i] = __uint_as_float(0xff800000u);
}

// t_ij for edge e, lane j. Identical code path in all consumers -> bitwise-consistent.
__device__ __forceinline__ float compute_t(int e, int c, int nb,
    const float* __restrict__ h0, const float* __restrict__ phi,
    const float* __restrict__ Wtcat, float gj, float bj, int j){
  float hc = h0[c*LAT + j], hj = h0[nb*LAT + j];
  float acc = 0.f;
  #pragma unroll 8
  for (int k = 0; k < LAT; k++){
    float hck = __shfl(hc, k), hjk = __shfl(hj, k);
    acc += hck * Wtcat[k*LAT + j] + hjk * Wtcat[(LAT + k)*LAT + j];
  }
  #pragma unroll
  for (int k = 0; k < D_RAD; k++) acc += phi[e*D_RAD + k] * Wtcat[(2*LAT + k)*LAT + j];
  acc *= RS136;
  float mu = wave_sum(acc) * (1.f/64.f);
  float va = wave_sum(acc*acc) * (1.f/64.f) - mu*mu;
  return (acc - mu) * rsqrtf(va + 1e-5f) * gj + bj;
}

// K1: pn = na@W_node, pc = na@W_center  (thread = (node, j))
__global__ void k_node_proj(const float* __restrict__ na,
                            const float* __restrict__ Wn,
                            const float* __restrict__ Wc,
                            float* __restrict__ pn, float* __restrict__ pc){
  int idx = blockIdx.x*blockDim.x + threadIdx.x;
  int n = idx >> 6, j = idx & 63;
  if (n >= N_NODES) return;
  float an = 0.f, ac = 0.f;
  #pragma unroll
  for (int k = 0; k < D_NODE; k++){
    float a = na[n*D_NODE + k];
    an += a * Wn[k*LAT + j];
    ac += a * Wc[k*LAT + j];
  }
  pn[idx] = an; pc[idx] = ac;
}

// K2: pe = pn[nb] * (phi@W_edge); m_node = segsum(pe)
__global__ void k_edge_msg(const float* __restrict__ phi,
                           const float* __restrict__ We,
                           const int* __restrict__ ec, const int* __restrict__ en,
                           const float* __restrict__ pn, float* __restrict__ mnode){
  int idx = blockIdx.x*blockDim.x + threadIdx.x;   // < E*64 exactly
  int e = idx >> 6, j = idx & 63;
  float d = 0.f;
  #pragma unroll
  for (int k = 0; k < D_RAD; k++) d += phi[e*D_RAD + k] * We[k*LAT + j];
  float pe = pn[en[e]*LAT + j] * d;
  atomicAdd(&mnode[ec[e]*LAT + j], pe);
}

// K3: h0 = h = LN([pc, m_node]@W_concat)   (wave per node)
__global__ void k_node_h(const float* __restrict__ pc, const float* __restrict__ mnode,
                         const float* __restrict__ Wcat,
                         const float* __restrict__ g, const float* __restrict__ b,
                         float* __restrict__ h0, float* __restrict__ h){
  int n = blockIdx.x*(blockDim.x >> 6) + (threadIdx.x >> 6);
  int j = threadIdx.x & 63;
  if (n >= N_NODES) return;
  float acc = 0.f;
  for (int k = 0; k < LAT; k++) acc += pc[n*LAT + k] * Wcat[k*LAT + j];
  for (int k = 0; k < LAT; k++) acc += mnode[n*LAT + k] * Wcat[(LAT + k)*LAT + j];
  float mu = wave_sum(acc) * (1.f/64.f);
  float va = wave_sum(acc*acc) * (1.f/64.f) - mu*mu;
  float v = (acc - mu) * rsqrtf(va + 1e-5f) * g[j] + b[j];
  h0[n*LAT + j] = v; h[n*LAT + j] = v;
}

// K4: edge_out = mlp(t, Wtij); w0 scatter into Xacc  (wave per edge, grid-stride)
__global__ void k_edge_tij(const float* __restrict__ h0,
                           const float* __restrict__ phi,
                           const float* __restrict__ sph,
                           const float* __restrict__ Wtcat,
                           const float* __restrict__ lg, const float* __restrict__ lb,
                           const float* __restrict__ Wtij,
                           const float* __restrict__ Wt0,
                           const float* __restrict__ Wh0,
                           const int* __restrict__ ec, const int* __restrict__ en,
                           float* __restrict__ Xacc,
                           float* __restrict__ edge_out){
  const int j = threadIdx.x & 63;
  const float gj = lg[j], bj = lb[j];
  int wid = blockIdx.x*(blockDim.x >> 6) + (threadIdx.x >> 6);
  int nw  = gridDim.x*(blockDim.x >> 6);
  for (int e = wid; e < N_EDGES; e += nw){
    int c = ec[e], nb = en[e];
    float t = compute_t(e, c, nb, h0, phi, Wtcat, gj, bj, j);
    float hj = h0[nb*LAT + j];
    float eo = 0.f, a0 = 0.f, b0 = 0.f;
    int jc = (j < WN_ENV) ? j : 0;
    #pragma unroll 8
    for (int k = 0; k < LAT; k++){
      float tk = __shfl(t, k), hjk = __shfl(hj, k);
      eo += tk  * Wtij[k*LAT + j];
      a0 += tk  * Wt0[k*WN_ENV + jc];
      b0 += hjk * Wh0[k*WN_ENV + jc];
    }
    edge_out[(long)e*LAT + j] = eo * 0.125f;
    float w0 = a0 * b0 * (0.125f * 0.125f);
    // env_weighter(sph, w0): out[m][d] = sph[d] * w0[irrep(d)*8+m], 72 vals at tt=m*9+d
    #pragma unroll
    for (int rep = 0; rep < 2; rep++){
      int tt = j + rep*64;
      int m = tt/9, d = tt - (tt/9)*9;
      int wi = (tt < 72) ? (irrep_of(d)*NHEAD + m) : 0;
      float wv = __shfl(w0, wi);
      if (tt < 72){
        float val = sph[e*D_SPH + d] * wv;
        atomicAdd(&Xacc[c*72 + tt], val);
      }
    }
  }
}

// K5: X = so3_norm(Xacc)   (wave per node)
__global__ void k_node_X0(const float* __restrict__ Xacc, float* __restrict__ X){
  int n = blockIdx.x*(blockDim.x >> 6) + (threadIdx.x >> 6);
  int j = threadIdx.x & 63;
  if (n >= N_NODES) return;
  float x0 = Xacc[n*72 + j];
  float x1 = (j < 8) ? Xacc[n*72 + 64 + j] : 0.f;
  float s0 = 0.f, s1 = 0.f, s2 = 0.f;
  { int d = j % 9; int k3 = irrep_of(d);
    if (k3 == 0) s0 = x0*x0; else if (k3 == 1) s1 = x0*x0; else s2 = x0*x0; }
  if (j < 8){ int d = (64 + j) % 9; int k3 = irrep_of(d);
    if (k3 == 0) s0 += x1*x1; else if (k3 == 1) s1 += x1*x1; else s2 += x1*x1; }
  s0 = wave_sum(s0); s1 = wave_sum(s1); s2 = wave_sum(s2);
  float sa = rsqrtf(s0*0.125f + 1e-5f), sb = rsqrtf(s1*0.125f + 1e-5f), sc = rsqrtf(s2*0.125f + 1e-5f);
  { int d = j % 9; int k3 = irrep_of(d);
    X[n*72 + j] = x0 * (k3==0 ? sa : (k3==1 ? sb : sc)); }
  if (j < 8){ int d = (64 + j) % 9; int k3 = irrep_of(d);
    X[n*72 + 64 + j] = x1 * (k3==0 ? sa : (k3==1 ? sb : sc)); }
}

// K6: attention logits + running max   (wave per edge; Wq/Wk staged in LDS)
__global__ void __launch_bounds__(256) k_att(const float* __restrict__ h0, const float* __restrict__ h,
                     const float* __restrict__ phi,
                     const float* __restrict__ Wtcat,
                     const float* __restrict__ lg, const float* __restrict__ lb,
                     const float* __restrict__ Wq, const float* __restrict__ Wk,
                     const int* __restrict__ ec, const int* __restrict__ en,
                     float* __restrict__ att, float* __restrict__ attmax){
  __shared__ float sq[64*128], sk[64*128];
  for (int i = threadIdx.x; i < 64*128; i += blockDim.x){ sq[i] = Wq[i]; sk[i] = Wk[i]; }
  __syncthreads();
  const int j = threadIdx.x & 63;
  const float gj = lg[j], bj = lb[j];
  int wid = blockIdx.x*(blockDim.x >> 6) + (threadIdx.x >> 6);
  int nw  = gridDim.x*(blockDim.x >> 6);
  for (int e = wid; e < N_EDGES; e += nw){
    int c = ec[e], nb = en[e];
    float t = compute_t(e, c, nb, h0, phi, Wtcat, gj, bj, j);
    float hj = h[nb*LAT + j];
    float q0 = 0.f, q1 = 0.f, k0 = 0.f, k1 = 0.f;
    #pragma unroll 8
    for (int k = 0; k < LAT; k++){
      float tk = __shfl(t, k), hk = __shfl(hj, k);
      q0 += tk * sq[k*128 + j];      q1 += tk * sq[k*128 + 64 + j];
      k0 += hk * sk[k*128 + j];      k1 += hk * sk[k*128 + 64 + j];
    }
    float p0 = q0*k0, p1 = q1*k1;
    #pragma unroll
    for (int off = 8; off; off >>= 1){ p0 += __shfl_xor(p0, off); p1 += __shfl_xor(p1, off); }
    if ((j & 15) == 0){
      int m = j >> 4;
      float a0 = 4.f*p0, a1 = 4.f*p1;
      att[(long)e*NHEAD + m] = a0;       att[(long)e*NHEAD + 4 + m] = a1;
      atomicMaxF(&attmax[c*NHEAD + m], a0);
      atomicMaxF(&attmax[c*NHEAD + 4 + m], a1);
    }
  }
}

// K7: env cols 0:216; hacc += env[:64]; x = d_sph + d_eq; fused softmax scatter:
//     ev = exp(att-amax); asum += ev; Xacc += x*ev
__global__ void __launch_bounds__(256) k_env(const float* __restrict__ h0, const float* __restrict__ h,
                     const float* __restrict__ X,
                     const float* __restrict__ phi,
                     const float* __restrict__ Wtcat,
                     const float* __restrict__ lg, const float* __restrict__ lb,
                     const float* __restrict__ Wrs, const float* __restrict__ Whj,
                     const float* __restrict__ sph,
                     const float* __restrict__ att, const float* __restrict__ attmax,
                     const int* __restrict__ ec, const int* __restrict__ en,
                     float* __restrict__ hacc, float* __restrict__ asum,
                     float* __restrict__ Xacc){
  __shared__ float srs[64*ENV_USED], shj[64*ENV_USED];
  __shared__ float senv[4][ENV_USED];
  __shared__ float sxn[4][72];
  for (int i = threadIdx.x; i < 64*ENV_USED; i += blockDim.x){
    int k = i / ENV_USED, o = i - k*ENV_USED;
    srs[i] = Wrs[k*GEN_W + o];
    shj[i] = Whj[k*GEN_W + o];
  }
  __syncthreads();
  const int j = threadIdx.x & 63, lw = threadIdx.x >> 6;
  const float gj = lg[j], bj = lb[j];
  int wid = blockIdx.x*(blockDim.x >> 6) + lw;
  int nw  = gridDim.x*(blockDim.x >> 6);
  int o3 = 192 + ((j < 24) ? j : 0);
  for (int e = wid; e < N_EDGES; e += nw){
    int c = ec[e], nb = en[e];
    float t = compute_t(e, c, nb, h0, phi, Wtcat, gj, bj, j);
    float hj = h[nb*LAT + j];
    float r0=0.f,r1=0.f,r2=0.f,r3=0.f, w0=0.f,w1=0.f,w2=0.f,w3=0.f;
    #pragma unroll 4
    for (int k = 0; k < LAT; k++){
      float tk = __shfl(t, k), hk = __shfl(hj, k);
      const float* rr = &srs[k*ENV_USED];
      const float* hh = &shj[k*ENV_USED];
      r0 += tk*rr[j];     r1 += tk*rr[64+j];
      r2 += tk*rr[128+j]; r3 += tk*rr[o3];
      w0 += hk*hh[j];     w1 += hk*hh[64+j];
      w2 += hk*hh[128+j]; w3 += hk*hh[o3];
    }
    float e0 = r0*w0*0.125f, e1 = r1*w1*0.125f, e2 = r2*w2*0.125f, e3 = r3*w3*0.125f;
    atomicAdd(&hacc[c*LAT + j], e0);
    senv[lw][j] = e0; senv[lw][64 + j] = e1; senv[lw][128 + j] = e2;
    if (j < 24) senv[lw][192 + j] = e3;
    sxn[lw][j] = X[nb*72 + j];
    if (j < 8) sxn[lw][64 + j] = X[nb*72 + 64 + j];
    __threadfence_block();
    if (j < NHEAD){
      float ev = __expf(att[(long)e*NHEAD + j] - attmax[c*NHEAD + j]);
      atomicAdd(&asum[c*NHEAD + j], ev);
    }
    #pragma unroll
    for (int rep = 0; rep < 2; rep++){
      int tt = j + rep*64;
      if (tt < 72){
        int m = tt/9, d = tt - m*9;
        int k3 = irrep_of(d);
        float ds = sph[e*D_SPH + d] * senv[lw][k3*8 + m];
        float dq = 0.f;
        #pragma unroll
        for (int i = 0; i < 8; i++) dq += sxn[lw][i*9 + d] * senv[lw][24 + k3*64 + i*8 + m];
        float ev = __expf(att[(long)e*NHEAD + m] - attmax[c*NHEAD + m]);
        atomicAdd(&Xacc[c*72 + tt], (ds + dq * RS8) * ev);
      }
    }
    __threadfence_block();
  }
}

// K8: h = LN(h+hacc); X = so3_norm(X + Xacc/(attsum+1e-12))   (wave per node)
__global__ void k_node_upd(const float* __restrict__ hacc, const float* __restrict__ attsum,
                           const float* __restrict__ Xacc,
                           const float* __restrict__ lg, const float* __restrict__ lb,
                           float* __restrict__ h, float* __restrict__ X){
  int n = blockIdx.x*(blockDim.x >> 6) + (threadIdx.x >> 6);
  int j = threadIdx.x & 63;
  if (n >= N_NODES) return;
  float hv = h[n*LAT + j] + hacc[n*LAT + j];
  float mu = wave_sum(hv) * (1.f/64.f);
  float va = wave_sum(hv*hv) * (1.f/64.f) - mu*mu;
  h[n*LAT + j] = (hv - mu) * rsqrtf(va + 1e-5f) * lg[j] + lb[j];

  float x0, x1 = 0.f;
  float s0 = 0.f, s1 = 0.f, s2 = 0.f;
  { int m = j/9, d = j - m*9;
    x0 = X[n*72 + j] + Xacc[n*72 + j] / (attsum[n*NHEAD + m] + 1e-12f);
    int k3 = irrep_of(d);
    if (k3 == 0) s0 = x0*x0; else if (k3 == 1) s1 = x0*x0; else s2 = x0*x0; }
  if (j < 8){ int tt = 64 + j; int m = tt/9, d = tt - m*9;
    x1 = X[n*72 + tt] + Xacc[n*72 + tt] / (attsum[n*NHEAD + m] + 1e-12f);
    int k3 = irrep_of(d);
    if (k3 == 0) s0 += x1*x1; else if (k3 == 1) s1 += x1*x1; else s2 += x1*x1; }
  s0 = wave_sum(s0); s1 = wave_sum(s1); s2 = wave_sum(s2);
  float sa = rsqrtf(s0*0.125f + 1e-5f), sb = rsqrtf(s1*0.125f + 1e-5f), sc = rsqrtf(s2*0.125f + 1e-5f);
  { int d = j % 9; int k3 = irrep_of(d);
    X[n*72 + j] = x0 * (k3==0 ? sa : (k3==1 ? sb : sc)); }
  if (j < 8){ int d = (64 + j) % 9; int k3 = irrep_of(d);
    X[n*72 + 64 + j] = x1 * (k3==0 ? sa : (k3==1 ? sb : sc)); }
}

// K9: w = h@W_hemb/8 -> (3,8,64); Xo = eq_linear(X,w); write node_out   (wave per node)
__global__ void k_node_out(const float* __restrict__ h, const float* __restrict__ X,
                           const float* __restrict__ Whemb,
                           float* __restrict__ out){
  __shared__ float sx[4][72];
  int n = blockIdx.x*(blockDim.x >> 6) + (threadIdx.x >> 6);
  int j = threadIdx.x & 63;   // output channel o
  int lw = threadIdx.x >> 6;
  if (n >= N_NODES) return;
  float hv = h[n*LAT + j];
  float wv[24];
  #pragma unroll
  for (int i = 0; i < 24; i++) wv[i] = 0.f;
  #pragma unroll 4
  for (int c = 0; c < LAT; c++){
    float hc = __shfl(hv, c);
    #pragma unroll
    for (int ki = 0; ki < 24; ki++)
      wv[ki] += hc * Whemb[c*WN_FIN + ki*64 + j];
  }
  sx[lw][j] = X[n*72 + j];
  if (j < 8) sx[lw][64 + j] = X[n*72 + 64 + j];
  __threadfence_block();
  #pragma unroll
  for (int d = 0; d < 9; d++){
    int k3 = irrep_of(d);
    float acc = 0.f;
    #pragma unroll
    for (int i = 0; i < 8; i++) acc += sx[lw][i*9 + d] * wv[k3*8 + i];
    acc *= 0.125f * RS8;
    int pos;
    if (d == 0)      pos = n*576 + j;
    else if (d < 4)  pos = n*576 + 64  + j*3 + (d - 1);
    else             pos = n*576 + 256 + j*5 + (d - 4);
    out[pos] = acc;
  }
}

// ---- workspace layout (floats) — total 6.08M floats = 24.3 MB ----
static const long O_H0   = 0;         // 640k
static const long O_H    = 640000;    // 640k
static const long O_X    = 1280000;   // 720k
static const long O_XACC = 2000000;   // 720k
static const long O_HACC = 2720000;   // 640k
static const long O_AMAX = 3360000;   // 80k
static const long O_ASUM = 3440000;   // 80k
static const long O_ATT  = 3520000;   // 2.56M (prologue aliases pn/pc/mn here)

extern "C" void kernel_launch(void* const* d_in, const int* in_sizes, int n_in,
                              void* d_out, int out_size, void* d_ws, size_t ws_size,
                              hipStream_t stream) {
  const float* na    = (const float*)d_in[0];
  const float* phi   = (const float*)d_in[1];
  const float* sph   = (const float*)d_in[2];
  // d_in[3] = edge_length (unused by reference)
  const float* Wn    = (const float*)d_in[4];
  const float* Wc    = (const float*)d_in[5];
  const float* Wcat  = (const float*)d_in[6];
  const float* We    = (const float*)d_in[7];
  const float* ln0g  = (const float*)d_in[8];
  const float* ln0b  = (const float*)d_in[9];
  const float* lneg  = (const float*)d_in[10];
  const float* lneb  = (const float*)d_in[11];
  const float* Wtcat = (const float*)d_in[12];
  const float* Wt0   = (const float*)d_in[13];
  const float* Wh0   = (const float*)d_in[14];
  const float* Wrs   = (const float*)d_in[15];
  const float* Whj   = (const float*)d_in[16];
  const float* lnlg  = (const float*)d_in[17];
  const float* lnlb  = (const float*)d_in[18];
  const float* Wq    = (const float*)d_in[19];
  const float* Wk    = (const float*)d_in[20];
  const float* Whemb = (const float*)d_in[21];
  const float* Wtij  = (const float*)d_in[22];
  const int* ec = (const int*)d_in[23];
  const int* en = (const int*)d_in[24];

  float* ws   = (float*)d_ws;
  float* h0   = ws + O_H0;
  float* h    = ws + O_H;
  float* X    = ws + O_X;
  float* Xacc = ws + O_XACC;
  float* hacc = ws + O_HACC;
  float* amax = ws + O_AMAX;
  float* asum = ws + O_ASUM;
  float* att  = ws + O_ATT;
  // prologue-only buffers alias the att region (dead before k_att runs)
  float* pn   = att;
  float* pc   = att + 640000;
  float* mn   = att + 1280000;

  float* out      = (float*)d_out;
  float* edge_out = out + (long)N_NODES*576;

  hipMemsetAsync(mn,   0, 640000*sizeof(float), stream);
  hipMemsetAsync(Xacc, 0, 720000*sizeof(float), stream);

  k_node_proj<<<(N_NODES*64)/256, 256, 0, stream>>>(na, Wn, Wc, pn, pc);
  k_edge_msg<<<(N_EDGES*64)/256, 256, 0, stream>>>(phi, We, ec, en, pn, mn);
  k_node_h<<<N_NODES/4, 256, 0, stream>>>(pc, mn, Wcat, ln0g, ln0b, h0, h);
  k_edge_tij<<<2048, 256, 0, stream>>>(h0, phi, sph, Wtcat, lneg, lneb, Wtij, Wt0, Wh0,
                                       ec, en, Xacc, edge_out);
  k_node_X0<<<N_NODES/4, 256, 0, stream>>>(Xacc, X);

  for (int l = 0; l < NL; l++){
    hipMemsetAsync(hacc, 0, 640000*sizeof(float), stream);
    hipMemsetAsync(Xacc, 0, 720000*sizeof(float), stream);
    hipMemsetAsync(asum, 0, 80000*sizeof(float), stream);
    fill_neg_inf<<<(80000 + 255)/256, 256, 0, stream>>>(amax, 80000);

    k_att<<<1024, 256, 0, stream>>>(h0, h, phi, Wtcat, lneg, lneb,
                                    Wq + l*64*128, Wk + l*64*128, ec, en, att, amax);
    k_env<<<1024, 256, 0, stream>>>(h0, h, X, phi, Wtcat, lneg, lneb,
                                    Wrs + l*64*GEN_W, Whj + l*64*GEN_W, sph,
                                    att, amax, ec, en, hacc, asum, Xacc);
    k_node_upd<<<N_NODES/4, 256, 0, stream>>>(hacc, asum, Xacc, lnlg + l*64, lnlb + l*64, h, X);
  }

  k_node_out<<<N_NODES/4, 256, 0, stream>>>(h, X, Whemb, out);
}

// Round 4
// 5658.002 us; speedup vs baseline: 1.6292x; 1.6292x over previous
//
#include <hip/hip_runtime.h>
#include <hip/hip_bf16.h>

#define N_NODES 10000
#define N_EDGES 320000
#define D_NODE 32
#define D_RAD 8
#define D_SPH 9
#define LAT 64
#define NHEAD 8
#define NL 2
#define GEN_W 280
#define WN_ENV 24

#define RS136 0.08574929257125442f   // 136^-0.5
#define RS8   0.35355339059327373f   // 8^-0.5

__device__ __forceinline__ int irrep_of(int d){ return (d==0)?0:((d<4)?1:2); }

__device__ __forceinline__ float wave_sum(float v){
  #pragma unroll
  for (int off=32; off; off>>=1) v += __shfl_xor(v, off);
  return v;
}

__device__ __forceinline__ void atomicMaxF(float* addr, float v){
  if (v >= 0.f) atomicMax((int*)addr, __float_as_int(v));
  else          atomicMin((unsigned int*)addr, __float_as_uint(v));
}

__global__ void fill_neg_inf(float* p, int n){
  int i = blockIdx.x*blockDim.x + threadIdx.x;
  if (i < n) p[i] = __uint_as_float(0xff800000u);
}

// K1: pn = na@W_node, pc = na@W_center
__global__ void k_node_proj(const float* __restrict__ na,
                            const float* __restrict__ Wn,
                            const float* __restrict__ Wc,
                            float* __restrict__ pn, float* __restrict__ pc){
  int idx = blockIdx.x*blockDim.x + threadIdx.x;
  int n = idx >> 6, j = idx & 63;
  if (n >= N_NODES) return;
  float an = 0.f, ac = 0.f;
  #pragma unroll
  for (int k = 0; k < D_NODE; k++){
    float a = na[n*D_NODE + k];
    an += a * Wn[k*LAT + j];
    ac += a * Wc[k*LAT + j];
  }
  pn[idx] = an; pc[idx] = ac;
}

// K2: pe = pn[nb] * (phi@W_edge); m_node = segsum(pe)
__global__ void k_edge_msg(const float* __restrict__ phi,
                           const float* __restrict__ We,
                           const int* __restrict__ ec, const int* __restrict__ en,
                           const float* __restrict__ pn, float* __restrict__ mnode){
  int idx = blockIdx.x*blockDim.x + threadIdx.x;
  int e = idx >> 6, j = idx & 63;
  float d = 0.f;
  #pragma unroll
  for (int k = 0; k < D_RAD; k++) d += phi[e*D_RAD + k] * We[k*LAT + j];
  float pe = pn[en[e]*LAT + j] * d;
  atomicAdd(&mnode[ec[e]*LAT + j], pe);
}

// K3: h0 = h = LN([pc, m_node]@W_concat)
__global__ void k_node_h(const float* __restrict__ pc, const float* __restrict__ mnode,
                         const float* __restrict__ Wcat,
                         const float* __restrict__ g, const float* __restrict__ b,
                         float* __restrict__ h0, float* __restrict__ h){
  int n = blockIdx.x*(blockDim.x >> 6) + (threadIdx.x >> 6);
  int j = threadIdx.x & 63;
  if (n >= N_NODES) return;
  float acc = 0.f;
  for (int k = 0; k < LAT; k++) acc += pc[n*LAT + k] * Wcat[k*LAT + j];
  for (int k = 0; k < LAT; k++) acc += mnode[n*LAT + k] * Wcat[(LAT + k)*LAT + j];
  float mu = wave_sum(acc) * (1.f/64.f);
  float va = wave_sum(acc*acc) * (1.f/64.f) - mu*mu;
  float v = (acc - mu) * rsqrtf(va + 1e-5f) * g[j] + b[j];
  h0[n*LAT + j] = v; h[n*LAT + j] = v;
}

// K4: t = LN(tcat@Wtcat); store T; edge_out; w0 scatter into Xacc.
// LDS-staged weights (63.5 KB -> 2 blocks/CU).
__global__ void __launch_bounds__(256) k_edge_tij(const float* __restrict__ h0,
                           const float* __restrict__ phi,
                           const float* __restrict__ sph,
                           const float* __restrict__ Wtcat,
                           const float* __restrict__ lg, const float* __restrict__ lb,
                           const float* __restrict__ Wtij,
                           const float* __restrict__ Wt0,
                           const float* __restrict__ Wh0,
                           const int* __restrict__ ec, const int* __restrict__ en,
                           float* __restrict__ T, float* __restrict__ Xacc,
                           float* __restrict__ edge_out){
  __shared__ float swt[136*64];   // Wtcat
  __shared__ float swij[64*64];   // Wtij
  __shared__ float sw0[64*24], sh0[64*24];
  for (int i = threadIdx.x; i < 136*64; i += 256) swt[i] = Wtcat[i];
  for (int i = threadIdx.x; i < 64*64;  i += 256) swij[i] = Wtij[i];
  for (int i = threadIdx.x; i < 64*24;  i += 256){ sw0[i] = Wt0[i]; sh0[i] = Wh0[i]; }
  __syncthreads();
  const int j = threadIdx.x & 63;
  const float gj = lg[j], bj = lb[j];
  int wid = blockIdx.x*4 + (threadIdx.x >> 6);
  int nw  = gridDim.x*4;
  for (int e = wid; e < N_EDGES; e += nw){
    int c = ec[e], nb = en[e];
    float hc = h0[c*LAT + j], hj = h0[nb*LAT + j];
    float acc = 0.f;
    #pragma unroll 8
    for (int k = 0; k < LAT; k++){
      float hck = __shfl(hc, k), hjk = __shfl(hj, k);
      acc += hck * swt[k*64 + j] + hjk * swt[(LAT + k)*64 + j];
    }
    #pragma unroll
    for (int k = 0; k < D_RAD; k++) acc += phi[e*D_RAD + k] * swt[(2*LAT + k)*64 + j];
    acc *= RS136;
    float mu = wave_sum(acc) * (1.f/64.f);
    float va = wave_sum(acc*acc) * (1.f/64.f) - mu*mu;
    float t = (acc - mu) * rsqrtf(va + 1e-5f) * gj + bj;
    T[(long)e*LAT + j] = t;

    float eo = 0.f, a0 = 0.f, b0 = 0.f;
    int jc = (j < WN_ENV) ? j : 0;
    #pragma unroll 8
    for (int k = 0; k < LAT; k++){
      float tk = __shfl(t, k), hjk = __shfl(hj, k);
      eo += tk  * swij[k*64 + j];
      a0 += tk  * sw0[k*24 + jc];
      b0 += hjk * sh0[k*24 + jc];
    }
    edge_out[(long)e*LAT + j] = eo * 0.125f;
    float w0 = a0 * b0 * (0.125f * 0.125f);
    #pragma unroll
    for (int rep = 0; rep < 2; rep++){
      int tt = j + rep*64;
      int m = tt/9, d = tt - (tt/9)*9;
      int wi = (tt < 72) ? (irrep_of(d)*NHEAD + m) : 0;
      float wv = __shfl(w0, wi);
      if (tt < 72){
        atomicAdd(&Xacc[c*72 + tt], sph[(long)e*D_SPH + d] * wv);
      }
    }
  }
}

// K5: X = so3_norm(Xacc)
__global__ void k_node_X0(const float* __restrict__ Xacc, float* __restrict__ X){
  int n = blockIdx.x*(blockDim.x >> 6) + (threadIdx.x >> 6);
  int j = threadIdx.x & 63;
  if (n >= N_NODES) return;
  float x0 = Xacc[n*72 + j];
  float x1 = (j < 8) ? Xacc[n*72 + 64 + j] : 0.f;
  float s0 = 0.f, s1 = 0.f, s2 = 0.f;
  { int d = j % 9; int k3 = irrep_of(d);
    if (k3 == 0) s0 = x0*x0; else if (k3 == 1) s1 = x0*x0; else s2 = x0*x0; }
  if (j < 8){ int d = (64 + j) % 9; int k3 = irrep_of(d);
    if (k3 == 0) s0 += x1*x1; else if (k3 == 1) s1 += x1*x1; else s2 += x1*x1; }
  s0 = wave_sum(s0); s1 = wave_sum(s1); s2 = wave_sum(s2);
  float sa = rsqrtf(s0*0.125f + 1e-5f), sb = rsqrtf(s1*0.125f + 1e-5f), sc = rsqrtf(s2*0.125f + 1e-5f);
  { int d = j % 9; int k3 = irrep_of(d);
    X[n*72 + j] = x0 * (k3==0 ? sa : (k3==1 ? sb : sc)); }
  if (j < 8){ int d = (64 + j) % 9; int k3 = irrep_of(d);
    X[n*72 + 64 + j] = x1 * (k3==0 ? sa : (k3==1 ? sb : sc)); }
}

// K6: attention logits + running max. Reads T; 2-edge ILP; f32 LDS weights (65.5 KB).
__global__ void __launch_bounds__(256) k_att(const float* __restrict__ T, const float* __restrict__ h,
                     const float* __restrict__ Wq, const float* __restrict__ Wk,
                     const int* __restrict__ ec, const int* __restrict__ en,
                     float* __restrict__ att, float* __restrict__ attmax){
  __shared__ float sq[64*128], sk[64*128];
  for (int i = threadIdx.x; i < 64*128; i += 256){ sq[i] = Wq[i]; sk[i] = Wk[i]; }
  __syncthreads();
  const int j = threadIdx.x & 63;
  int wid = blockIdx.x*4 + (threadIdx.x >> 6);
  int nw  = gridDim.x*4;
  for (int p = wid; p < N_EDGES/2; p += nw){
    int e0 = 2*p, e1 = 2*p + 1;
    int c0 = ec[e0], nb0 = en[e0];
    int c1 = ec[e1], nb1 = en[e1];
    float t0 = T[(long)e0*LAT + j], t1 = T[(long)e1*LAT + j];
    float h0v = h[nb0*LAT + j],     h1v = h[nb1*LAT + j];
    float q00=0,q01=0,k00=0,k01=0, q10=0,q11=0,k10=0,k11=0;
    #pragma unroll 8
    for (int k = 0; k < LAT; k++){
      float wq0 = sq[k*128 + j], wq1 = sq[k*128 + 64 + j];
      float wk0 = sk[k*128 + j], wk1 = sk[k*128 + 64 + j];
      float tk0 = __shfl(t0, k), tk1 = __shfl(t1, k);
      float hk0 = __shfl(h0v, k), hk1 = __shfl(h1v, k);
      q00 += tk0*wq0; q01 += tk0*wq1; k00 += hk0*wk0; k01 += hk0*wk1;
      q10 += tk1*wq0; q11 += tk1*wq1; k10 += hk1*wk0; k11 += hk1*wk1;
    }
    float p00 = q00*k00, p01 = q01*k01, p10 = q10*k10, p11 = q11*k11;
    #pragma unroll
    for (int off = 8; off; off >>= 1){
      p00 += __shfl_xor(p00, off); p01 += __shfl_xor(p01, off);
      p10 += __shfl_xor(p10, off); p11 += __shfl_xor(p11, off);
    }
    if ((j & 15) == 0){
      int m = j >> 4;
      float a00 = 4.f*p00, a01 = 4.f*p01, a10 = 4.f*p10, a11 = 4.f*p11;
      att[(long)e0*NHEAD + m] = a00;     att[(long)e0*NHEAD + 4 + m] = a01;
      att[(long)e1*NHEAD + m] = a10;     att[(long)e1*NHEAD + 4 + m] = a11;
      atomicMaxF(&attmax[c0*NHEAD + m], a00);
      atomicMaxF(&attmax[c0*NHEAD + 4 + m], a01);
      atomicMaxF(&attmax[c1*NHEAD + m], a10);
      atomicMaxF(&attmax[c1*NHEAD + 4 + m], a11);
    }
  }
}

// K7a: env cols A = [0:64)+[88:120)+[152:184); hacc scatter; d_sph + d_eq(i<4); asum; Xacc part.
// slot->col: s<64 -> s; s<96 -> s+24; else s+56. LDS 65.5KB+7KB -> 2 blocks/CU.
__global__ void __launch_bounds__(256) k_envA(const float* __restrict__ T, const float* __restrict__ h,
                     const float* __restrict__ X,
                     const float* __restrict__ Wrs, const float* __restrict__ Whj,
                     const float* __restrict__ sph,
                     const float* __restrict__ att, const float* __restrict__ attmax,
                     const int* __restrict__ ec, const int* __restrict__ en,
                     float* __restrict__ hacc, float* __restrict__ asum,
                     float* __restrict__ Xacc){
  __shared__ float srs[64*128], shw[64*128];
  __shared__ float senv[4][2][128];
  __shared__ float sxn[4][2][72];
  for (int i = threadIdx.x; i < 64*128; i += 256){
    int k = i >> 7, s = i & 127;
    int c = s + (s < 64 ? 0 : (s < 96 ? 24 : 56));
    srs[i] = Wrs[k*GEN_W + c];
    shw[i] = Whj[k*GEN_W + c];
  }
  __syncthreads();
  const int j = threadIdx.x & 63, lw = threadIdx.x >> 6;
  int wid = blockIdx.x*4 + lw;
  int nw  = gridDim.x*4;
  for (int p = wid; p < N_EDGES/2; p += nw){
    int e0 = 2*p, e1 = 2*p + 1;
    int c0 = ec[e0], nb0 = en[e0];
    int c1 = ec[e1], nb1 = en[e1];
    float t0 = T[(long)e0*LAT + j], t1 = T[(long)e1*LAT + j];
    float h0v = h[nb0*LAT + j],     h1v = h[nb1*LAT + j];
    float rA0=0,rB0=0,wA0=0,wB0=0, rA1=0,rB1=0,wA1=0,wB1=0;
    #pragma unroll 8
    for (int k = 0; k < LAT; k++){
      float wr0 = srs[k*128 + j], wr1 = srs[k*128 + 64 + j];
      float wh0 = shw[k*128 + j], wh1 = shw[k*128 + 64 + j];
      float tk0 = __shfl(t0, k), tk1 = __shfl(t1, k);
      float hk0 = __shfl(h0v, k), hk1 = __shfl(h1v, k);
      rA0 += tk0*wr0; rB0 += tk0*wr1; wA0 += hk0*wh0; wB0 += hk0*wh1;
      rA1 += tk1*wr0; rB1 += tk1*wr1; wA1 += hk1*wh0; wB1 += hk1*wh1;
    }
    float eA0 = rA0*wA0*0.125f, eB0 = rB0*wB0*0.125f;
    float eA1 = rA1*wA1*0.125f, eB1 = rB1*wB1*0.125f;
    atomicAdd(&hacc[c0*LAT + j], eA0);
    atomicAdd(&hacc[c1*LAT + j], eA1);
    senv[lw][0][j] = eA0; senv[lw][0][64 + j] = eB0;
    senv[lw][1][j] = eA1; senv[lw][1][64 + j] = eB1;
    sxn[lw][0][j] = X[nb0*72 + j]; if (j < 8) sxn[lw][0][64 + j] = X[nb0*72 + 64 + j];
    sxn[lw][1][j] = X[nb1*72 + j]; if (j < 8) sxn[lw][1][64 + j] = X[nb1*72 + 64 + j];
    __threadfence_block();
    if (j < NHEAD){
      float ev = __expf(att[(long)e0*NHEAD + j] - attmax[c0*NHEAD + j]);
      atomicAdd(&asum[c0*NHEAD + j], ev);
    } else if (j < 2*NHEAD){
      int m = j - NHEAD;
      float ev = __expf(att[(long)e1*NHEAD + m] - attmax[c1*NHEAD + m]);
      atomicAdd(&asum[c1*NHEAD + m], ev);
    }
    #pragma unroll
    for (int x = 0; x < 2; x++){
      long e = 2*p + x; int cc = x ? c1 : c0;
      #pragma unroll
      for (int rep = 0; rep < 2; rep++){
        int tt = j + rep*64;
        if (tt < 72){
          int m = tt/9, d = tt - m*9, k3 = irrep_of(d);
          float ds = sph[e*D_SPH + d] * senv[lw][x][k3*8 + m];
          int sb = (k3==0) ? 24 : ((k3==1) ? 64 : 96);
          float dq = 0.f;
          #pragma unroll
          for (int i = 0; i < 4; i++) dq += sxn[lw][x][i*9 + d] * senv[lw][x][sb + i*8 + m];
          float ev = __expf(att[e*NHEAD + m] - attmax[cc*NHEAD + m]);
          atomicAdd(&Xacc[cc*72 + tt], (ds + dq*RS8) * ev);
        }
      }
    }
    __threadfence_block();
  }
}

// K7b: env cols B = [56:88)+[120:152)+[184:216) -> d_eq(i>=4) part. LDS 49KB -> 3 blocks/CU.
// slot->col: s<32 -> s+56; s<64 -> s+88; else s+120.
__global__ void __launch_bounds__(256) k_envB(const float* __restrict__ T, const float* __restrict__ h,
                     const float* __restrict__ X,
                     const float* __restrict__ Wrs, const float* __restrict__ Whj,
                     const float* __restrict__ att, const float* __restrict__ attmax,
                     const int* __restrict__ ec, const int* __restrict__ en,
                     float* __restrict__ Xacc){
  __shared__ float srs[64*96], shw[64*96];
  __shared__ float senv[4][2][96];
  __shared__ float sxn[4][2][72];
  for (int i = threadIdx.x; i < 64*96; i += 256){
    int k = i / 96, s = i - k*96;
    int c = s + (s < 32 ? 56 : (s < 64 ? 88 : 120));
    srs[i] = Wrs[k*GEN_W + c];
    shw[i] = Whj[k*GEN_W + c];
  }
  __syncthreads();
  const int j = threadIdx.x & 63, lw = threadIdx.x >> 6;
  int wid = blockIdx.x*4 + lw;
  int nw  = gridDim.x*4;
  for (int p = wid; p < N_EDGES/2; p += nw){
    int e0 = 2*p, e1 = 2*p + 1;
    int c0 = ec[e0], nb0 = en[e0];
    int c1 = ec[e1], nb1 = en[e1];
    float t0 = T[(long)e0*LAT + j], t1 = T[(long)e1*LAT + j];
    float h0v = h[nb0*LAT + j],     h1v = h[nb1*LAT + j];
    float rA0=0,rB0=0,wA0=0,wB0=0, rA1=0,rB1=0,wA1=0,wB1=0;
    #pragma unroll 8
    for (int k = 0; k < LAT; k++){
      float wr0 = srs[k*96 + j];
      float wh0 = shw[k*96 + j];
      float wr1 = (j < 32) ? srs[k*96 + 64 + j] : 0.f;
      float wh1 = (j < 32) ? shw[k*96 + 64 + j] : 0.f;
      float tk0 = __shfl(t0, k), tk1 = __shfl(t1, k);
      float hk0 = __shfl(h0v, k), hk1 = __shfl(h1v, k);
      rA0 += tk0*wr0; rB0 += tk0*wr1; wA0 += hk0*wh0; wB0 += hk0*wh1;
      rA1 += tk1*wr0; rB1 += tk1*wr1; wA1 += hk1*wh0; wB1 += hk1*wh1;
    }
    senv[lw][0][j] = rA0*wA0*0.125f;
    senv[lw][1][j] = rA1*wA1*0.125f;
    if (j < 32){
      senv[lw][0][64 + j] = rB0*wB0*0.125f;
      senv[lw][1][64 + j] = rB1*wB1*0.125f;
    }
    sxn[lw][0][j] = X[nb0*72 + j]; if (j < 8) sxn[lw][0][64 + j] = X[nb0*72 + 64 + j];
    sxn[lw][1][j] = X[nb1*72 + j]; if (j < 8) sxn[lw][1][64 + j] = X[nb1*72 + 64 + j];
    __threadfence_block();
    #pragma unroll
    for (int x = 0; x < 2; x++){
      long e = 2*p + x; int cc = x ? c1 : c0;
      #pragma unroll
      for (int rep = 0; rep < 2; rep++){
        int tt = j + rep*64;
        if (tt < 72){
          int m = tt/9, d = tt - m*9, k3 = irrep_of(d);
          int sb = (k3==0) ? 0 : ((k3==1) ? 32 : 64);
          float dq = 0.f;
          #pragma unroll
          for (int i = 0; i < 4; i++) dq += sxn[lw][x][(i+4)*9 + d] * senv[lw][x][sb + i*8 + m];
          float ev = __expf(att[e*NHEAD + m] - attmax[cc*NHEAD + m]);
          atomicAdd(&Xacc[cc*72 + tt], dq*RS8*ev);
        }
      }
    }
    __threadfence_block();
  }
}

// K8: h = LN(h+hacc); X = so3_norm(X + Xacc/(attsum+1e-12))
__global__ void k_node_upd(const float* __restrict__ hacc, const float* __restrict__ attsum,
                           const float* __restrict__ Xacc,
                           const float* __restrict__ lg, const float* __restrict__ lb,
                           float* __restrict__ h, float* __restrict__ X){
  int n = blockIdx.x*(blockDim.x >> 6) + (threadIdx.x >> 6);
  int j = threadIdx.x & 63;
  if (n >= N_NODES) return;
  float hv = h[n*LAT + j] + hacc[n*LAT + j];
  float mu = wave_sum(hv) * (1.f/64.f);
  float va = wave_sum(hv*hv) * (1.f/64.f) - mu*mu;
  h[n*LAT + j] = (hv - mu) * rsqrtf(va + 1e-5f) * lg[j] + lb[j];

  float x0, x1 = 0.f;
  float s0 = 0.f, s1 = 0.f, s2 = 0.f;
  { int m = j/9, d = j - m*9;
    x0 = X[n*72 + j] + Xacc[n*72 + j] / (attsum[n*NHEAD + m] + 1e-12f);
    int k3 = irrep_of(d);
    if (k3 == 0) s0 = x0*x0; else if (k3 == 1) s1 = x0*x0; else s2 = x0*x0; }
  if (j < 8){ int tt = 64 + j; int m = tt/9, d = tt - m*9;
    x1 = X[n*72 + tt] + Xacc[n*72 + tt] / (attsum[n*NHEAD + m] + 1e-12f);
    int k3 = irrep_of(d);
    if (k3 == 0) s0 += x1*x1; else if (k3 == 1) s1 += x1*x1; else s2 += x1*x1; }
  s0 = wave_sum(s0); s1 = wave_sum(s1); s2 = wave_sum(s2);
  float sa = rsqrtf(s0*0.125f + 1e-5f), sb = rsqrtf(s1*0.125f + 1e-5f), sc = rsqrtf(s2*0.125f + 1e-5f);
  { int d = j % 9; int k3 = irrep_of(d);
    X[n*72 + j] = x0 * (k3==0 ? sa : (k3==1 ? sb : sc)); }
  if (j < 8){ int d = (64 + j) % 9; int k3 = irrep_of(d);
    X[n*72 + 64 + j] = x1 * (k3==0 ? sa : (k3==1 ? sb : sc)); }
}

// K9: w = h@W_hemb/8 -> (3,8,64); Xo = eq_linear(X,w); node_out
__global__ void k_node_out(const float* __restrict__ h, const float* __restrict__ X,
                           const float* __restrict__ Whemb,
                           float* __restrict__ out){
  __shared__ float sx[4][72];
  int n = blockIdx.x*(blockDim.x >> 6) + (threadIdx.x >> 6);
  int j = threadIdx.x & 63;
  int lw = threadIdx.x >> 6;
  if (n >= N_NODES) return;
  float hv = h[n*LAT + j];
  float wv[24];
  #pragma unroll
  for (int i = 0; i < 24; i++) wv[i] = 0.f;
  #pragma unroll 4
  for (int c = 0; c < LAT; c++){
    float hc = __shfl(hv, c);
    #pragma unroll
    for (int ki = 0; ki < 24; ki++)
      wv[ki] += hc * Whemb[c*1536 + ki*64 + j];
  }
  sx[lw][j] = X[n*72 + j];
  if (j < 8) sx[lw][64 + j] = X[n*72 + 64 + j];
  __threadfence_block();
  #pragma unroll
  for (int d = 0; d < 9; d++){
    int k3 = irrep_of(d);
    float acc = 0.f;
    #pragma unroll
    for (int i = 0; i < 8; i++) acc += sx[lw][i*9 + d] * wv[k3*8 + i];
    acc *= 0.125f * RS8;
    int pos;
    if (d == 0)      pos = n*576 + j;
    else if (d < 4)  pos = n*576 + 64  + j*3 + (d - 1);
    else             pos = n*576 + 256 + j*5 + (d - 4);
    out[pos] = acc;
  }
}

// ---- workspace layout (floats) — total 26.56M floats = 106.2 MB ----
static const long O_T    = 0;          // 20.48M  (E*64)
static const long O_ATT  = 20480000;   // 2.56M   (E*8) ; prologue pn/pc/mn alias here
static const long O_H0   = 23040000;   // 640k
static const long O_H    = 23680000;   // 640k
static const long O_X    = 24320000;   // 720k
static const long O_XACC = 25040000;   // 720k
static const long O_HACC = 25760000;   // 640k
static const long O_AMAX = 26400000;   // 80k
static const long O_ASUM = 26480000;   // 80k

extern "C" void kernel_launch(void* const* d_in, const int* in_sizes, int n_in,
                              void* d_out, int out_size, void* d_ws, size_t ws_size,
                              hipStream_t stream) {
  const float* na    = (const float*)d_in[0];
  const float* phi   = (const float*)d_in[1];
  const float* sph   = (const float*)d_in[2];
  const float* Wn    = (const float*)d_in[4];
  const float* Wc    = (const float*)d_in[5];
  const float* Wcat  = (const float*)d_in[6];
  const float* We    = (const float*)d_in[7];
  const float* ln0g  = (const float*)d_in[8];
  const float* ln0b  = (const float*)d_in[9];
  const float* lneg  = (const float*)d_in[10];
  const float* lneb  = (const float*)d_in[11];
  const float* Wtcat = (const float*)d_in[12];
  const float* Wt0   = (const float*)d_in[13];
  const float* Wh0   = (const float*)d_in[14];
  const float* Wrs   = (const float*)d_in[15];
  const float* Whj   = (const float*)d_in[16];
  const float* lnlg  = (const float*)d_in[17];
  const float* lnlb  = (const float*)d_in[18];
  const float* Wq    = (const float*)d_in[19];
  const float* Wk    = (const float*)d_in[20];
  const float* Whemb = (const float*)d_in[21];
  const float* Wtij  = (const float*)d_in[22];
  const int* ec = (const int*)d_in[23];
  const int* en = (const int*)d_in[24];

  float* ws   = (float*)d_ws;
  float* T    = ws + O_T;
  float* att  = ws + O_ATT;
  float* h0   = ws + O_H0;
  float* h    = ws + O_H;
  float* X    = ws + O_X;
  float* Xacc = ws + O_XACC;
  float* hacc = ws + O_HACC;
  float* amax = ws + O_AMAX;
  float* asum = ws + O_ASUM;
  // prologue-only buffers alias the att region (dead before k_att runs)
  float* pn   = att;
  float* pc   = att + 640000;
  float* mn   = att + 1280000;

  float* out      = (float*)d_out;
  float* edge_out = out + (long)N_NODES*576;

  hipMemsetAsync(mn,   0, 640000*sizeof(float), stream);
  hipMemsetAsync(Xacc, 0, 720000*sizeof(float), stream);

  k_node_proj<<<(N_NODES*64)/256, 256, 0, stream>>>(na, Wn, Wc, pn, pc);
  k_edge_msg<<<(N_EDGES*64)/256, 256, 0, stream>>>(phi, We, ec, en, pn, mn);
  k_node_h<<<N_NODES/4, 256, 0, stream>>>(pc, mn, Wcat, ln0g, ln0b, h0, h);
  k_edge_tij<<<2048, 256, 0, stream>>>(h0, phi, sph, Wtcat, lneg, lneb, Wtij, Wt0, Wh0,
                                       ec, en, T, Xacc, edge_out);
  k_node_X0<<<N_NODES/4, 256, 0, stream>>>(Xacc, X);

  for (int l = 0; l < NL; l++){
    hipMemsetAsync(hacc, 0, 640000*sizeof(float), stream);
    hipMemsetAsync(Xacc, 0, 720000*sizeof(float), stream);
    hipMemsetAsync(asum, 0, 80000*sizeof(float), stream);
    fill_neg_inf<<<(80000 + 255)/256, 256, 0, stream>>>(amax, 80000);

    k_att<<<1024, 256, 0, stream>>>(T, h, Wq + l*64*128, Wk + l*64*128, ec, en, att, amax);
    k_envA<<<1024, 256, 0, stream>>>(T, h, X, Wrs + l*64*GEN_W, Whj + l*64*GEN_W, sph,
                                     att, amax, ec, en, hacc, asum, Xacc);
    k_envB<<<1024, 256, 0, stream>>>(T, h, X, Wrs + l*64*GEN_W, Whj + l*64*GEN_W,
                                     att, amax, ec, en, Xacc);
    k_node_upd<<<N_NODES/4, 256, 0, stream>>>(hacc, asum, Xacc, lnlg + l*64, lnlb + l*64, h, X);
  }

  k_node_out<<<N_NODES/4, 256, 0, stream>>>(h, X, Whemb, out);
}